// Round 1
// baseline (2893.338 us; speedup 1.0000x reference)
//
#include <hip/hip_runtime.h>
#include <hip/hip_cooperative_groups.h>
#include <cstdint>
#include <cstddef>

namespace cg = cooperative_groups;

// ---------------- problem constants ----------------
static constexpr int NB  = 32;      // batch
static constexpr int NT  = 22;      // caption length T
static constexpr int NP  = 196;     // pixels 14*14
static constexpr int NDE = 2048;    // encoder dim
static constexpr int NE  = 512;     // embed dim
static constexpr int NH  = 512;     // hidden
static constexpr int NA  = 512;     // attention dim
static constexpr int NV  = 30000;   // vocab
static constexpr int NTD = 20;      // Tdec = T-2
static constexpr int NKX = 3072;    // E + DE + H (concat x | h)

// ---------------- output offsets (floats) ----------------
static constexpr size_t OUT_PRED  = 0;
static constexpr size_t OUT_ALPHA = (size_t)NB*NTD*NV;            // 19,200,000
static constexpr size_t OUT_CAPS  = OUT_ALPHA + (size_t)NB*NTD*NP;// 19,325,440
static constexpr size_t OUT_LEN   = OUT_CAPS + (size_t)NB*NT;     // 19,326,144
static constexpr size_t OUT_SIDX  = OUT_LEN + NB;                 // 19,326,176

// ---------------- ws layout (float offsets) ----------------
// int region: [0,32) sidx | [32,64) declen | [64,768) caps_i
static constexpr size_t WS_H     = 768;
static constexpr size_t WS_C     = 17152;
static constexpr size_t WS_MEAN  = 33536;
static constexpr size_t WS_XCATB = 121728;    // bf16 [32][3072]
static constexpr size_t WS_ATT1B = 170880;    // bf16 [6272][512]
static constexpr size_t WS_ENCB  = 1776512;   // bf16 [32][196][2048]
static constexpr size_t WS_W2B   = 8199040;   // bf16 [2048][3072]
static constexpr size_t WS_WDAT  = 11344768;  // bf16 [512][512]   (WdaT[n][k])
static constexpr size_t WS_WEAT  = 11475840;  // bf16 [512][2048]  (WeaT[n][k])
static constexpr size_t WS_WOUTT = 12000128;  // bf16 [30000][512] (WoutT[n][k])
static constexpr size_t WS_WFBT  = 19680128;  // bf16 [2048][512]  (WfbT[d][k])
static constexpr size_t WS_MEANB = 20204416;  // bf16 [32][2048]
static constexpr size_t WS_WH0T  = 20237184;  // bf16 [512][2048]
static constexpr size_t WS_WC0T  = 20761472;  // bf16 [512][2048]
static constexpr size_t WS_HIST  = 21285760;  // bf16 [640][512] (h history, m=t*32+b)
// end = 21,449,600 floats ~= 81.8 MB

// ---------------- MFMA types & helpers ----------------
typedef __attribute__((ext_vector_type(8))) short bf16x8;
typedef __attribute__((ext_vector_type(4))) float f32x4;
#define MFMA16(a,b,c) __builtin_amdgcn_mfma_f32_16x16x32_bf16(a,b,c,0,0,0)

__device__ __forceinline__ float bf2f(unsigned short u) {
    return __uint_as_float(((unsigned)u) << 16);
}
__device__ __forceinline__ unsigned short f2bf(float f) {
    unsigned u = __float_as_uint(f);
    u += 0x7FFF + ((u >> 16) & 1);      // RTNE
    return (unsigned short)(u >> 16);
}
__device__ __forceinline__ float sigm(float x) { return 1.f / (1.f + expf(-x)); }

// ---------------- prelude kernels ----------------

__global__ void k_sort(const int* __restrict__ cap, const int* __restrict__ clen,
                       float* __restrict__ out, int* __restrict__ wsi) {
    __shared__ int slen[NB], ssid[NB];
    int i = threadIdx.x;
    if (i < NB) slen[i] = clen[i];
    __syncthreads();
    if (i < NB) {
        int li = slen[i], r = 0;
        for (int j = 0; j < NB; j++) {
            int lj = slen[j];
            if (lj > li || (lj == li && j < i)) r++;
        }
        ssid[r] = i;
    }
    __syncthreads();
    if (i < NB) {
        int src = ssid[i];
        wsi[i] = src;
        int L = slen[src];
        wsi[NB + i] = L - 1;
        out[OUT_LEN + i]  = (float)L;
        out[OUT_SIDX + i] = (float)src;
        for (int tt = 0; tt < NT; tt++) {
            int tok = cap[tt * NB + src];
            wsi[2 * NB + i * NT + tt] = tok;
            out[OUT_CAPS + i * NT + tt] = (float)tok;
        }
    }
}

// sorted-gather feat -> enc bf16, plus per-(b,d) mean (fp32 + bf16)
__global__ void k_prep(const float* __restrict__ feat, const int* __restrict__ wsi,
                       unsigned short* __restrict__ encb, float* __restrict__ mean,
                       unsigned short* __restrict__ meanb) {
    int g = blockIdx.x * 256 + threadIdx.x;   // 65536 = 32*2048
    int b = g >> 11, d = g & 2047;
    const float* src = feat + (size_t)wsi[b] * (NP * NDE) + d;
    unsigned short* dst = encb + (size_t)b * (NP * NDE) + d;
    float s = 0.f;
    for (int p = 0; p < NP; p++) {
        float v = src[(size_t)p * NDE];
        s += v;
        dst[(size_t)p * NDE] = f2bf(v);
    }
    float m = s * (1.0f / 196.0f);
    mean[(size_t)b * NDE + d] = m;
    meanb[(size_t)b * NDE + d] = f2bf(m);
}

// h0/c0 via MFMA: M=32, N=512 each; 16 blocks (8 h-tiles, 8 c-tiles)
__global__ __launch_bounds__(256) void k_h0c0m(const unsigned short* __restrict__ meanb,
        const unsigned short* __restrict__ WH0T, const unsigned short* __restrict__ WC0T,
        const float* __restrict__ bh0, const float* __restrict__ bc0,
        float* __restrict__ h, float* __restrict__ c, unsigned short* __restrict__ xcatb) {
    int tid = threadIdx.x;
    int w = tid >> 6, lane = tid & 63, ln = lane & 15, quad = lane >> 4;
    int which = blockIdx.x >> 3;
    int n = (blockIdx.x & 7) * 64 + w * 16 + ln;
    const unsigned short* WT = which ? WC0T : WH0T;
    f32x4 acc0 = {0.f, 0.f, 0.f, 0.f}, acc1 = {0.f, 0.f, 0.f, 0.f};
    for (int k0 = 0; k0 < NDE; k0 += 32) {
        bf16x8 bfr = *(const bf16x8*)(WT + (size_t)n * NDE + k0 + quad * 8);
        bf16x8 a0 = *(const bf16x8*)(meanb + (size_t)ln * NDE + k0 + quad * 8);
        bf16x8 a1 = *(const bf16x8*)(meanb + (size_t)(16 + ln) * NDE + k0 + quad * 8);
        acc0 = MFMA16(a0, bfr, acc0);
        acc1 = MFMA16(a1, bfr, acc1);
    }
    float bias = which ? bc0[n] : bh0[n];
    #pragma unroll
    for (int r = 0; r < 4; r++) {
        int b0r = quad * 4 + r;
        float v0 = acc0[r] + bias, v1 = acc1[r] + bias;
        if (which) {
            c[(size_t)b0r * NH + n] = v0;
            c[(size_t)(16 + b0r) * NH + n] = v1;
        } else {
            h[(size_t)b0r * NH + n] = v0;
            h[(size_t)(16 + b0r) * NH + n] = v1;
            xcatb[(size_t)b0r * NKX + 2560 + n] = f2bf(v0);
            xcatb[(size_t)(16 + b0r) * NKX + 2560 + n] = f2bf(v1);
        }
    }
}

// W2b[n][k] = bf16( k<2560 ? Wih[n][k] : Whh[n][k-2560] )
__global__ void k_w2b(const float* __restrict__ Wih, const float* __restrict__ Whh,
                      unsigned short* __restrict__ W2b) {
    int k = blockIdx.x * 256 + threadIdx.x;   // 0..3071
    int n = blockIdx.y;                       // 0..2047
    float v = (k < 2560) ? Wih[(size_t)n * 2560 + k]
                         : Whh[(size_t)n * 512 + (k - 2560)];
    W2b[(size_t)n * NKX + k] = f2bf(v);
}

// fp32 [R][C] -> bf16 [C][R] (R multiple of 32; C bounds-checked)
__global__ void k_trbf(const float* __restrict__ src, unsigned short* __restrict__ dst,
                       int R, int C) {
    __shared__ float s[32][33];
    int c0 = blockIdx.x * 32, r0 = blockIdx.y * 32;
    int tx = threadIdx.x & 31, ty = threadIdx.x >> 5;  // ty 0..7
    #pragma unroll
    for (int i = 0; i < 4; i++) {
        int rr = ty * 4 + i;
        int cc = c0 + tx;
        s[rr][tx] = (cc < C) ? src[(size_t)(r0 + rr) * C + cc] : 0.f;
    }
    __syncthreads();
    #pragma unroll
    for (int i = 0; i < 4; i++) {
        int cc = ty * 4 + i;
        int cg = c0 + cc;
        if (cg < C) dst[(size_t)cg * R + r0 + tx] = f2bf(s[tx][cc]);
    }
}

// att1 = enc @ Wea + bea  (MFMA bf16): M=6272, N=512, K=2048 -> att1b bf16
__global__ __launch_bounds__(256) void k_att1(const unsigned short* __restrict__ encb,
        const unsigned short* __restrict__ WeaT, const float* __restrict__ bea,
        unsigned short* __restrict__ att1b) {
    __shared__ unsigned short As[64 * 40];    // 64 m x 32 k, stride 40
    int m0 = blockIdx.x * 64;
    int nb = blockIdx.y * 256;
    int tid = threadIdx.x;
    int w = tid >> 6, lane = tid & 63, ln = lane & 15, quad = lane >> 4;
    int nbase = nb + w * 64;
    f32x4 acc[4][4] = {};
    int sm = tid >> 2, sc = tid & 3;
    for (int k0 = 0; k0 < NDE; k0 += 32) {
        bf16x8 v = *(const bf16x8*)(encb + (size_t)(m0 + sm) * NDE + k0 + sc * 8);
        __syncthreads();
        *(bf16x8*)(&As[sm * 40 + sc * 8]) = v;
        __syncthreads();
        bf16x8 a[4], bb[4];
        #pragma unroll
        for (int i = 0; i < 4; i++)
            a[i] = *(const bf16x8*)(&As[(i * 16 + ln) * 40 + quad * 8]);
        #pragma unroll
        for (int j = 0; j < 4; j++)
            bb[j] = *(const bf16x8*)(WeaT + (size_t)(nbase + j * 16 + ln) * NDE + k0 + quad * 8);
        #pragma unroll
        for (int i = 0; i < 4; i++)
            #pragma unroll
            for (int j = 0; j < 4; j++)
                acc[i][j] = MFMA16(a[i], bb[j], acc[i][j]);
    }
    #pragma unroll
    for (int i = 0; i < 4; i++)
        #pragma unroll
        for (int j = 0; j < 4; j++) {
            int n = nbase + j * 16 + ln;
            float be = bea[n];
            #pragma unroll
            for (int r = 0; r < 4; r++) {
                int m = m0 + i * 16 + quad * 4 + r;
                att1b[(size_t)m * NA + n] = f2bf(acc[i][j][r] + be);
            }
        }
}

// ---------------- persistent step kernel ----------------
// 128 blocks x 512 threads, cooperative launch. Per step:
//   phase 1 (all 128 blocks, block=(b, dgrp)): att2 + scores + softmax +
//            alpha-out + emb gather + awe + gate -> xcatb
//   grid.sync()
//   phase 2 (blocks 0..31, j0=bid*16): gates MFMA GEMM + LSTM pointwise ->
//            h, c, histb, xcat h-part
//   grid.sync()
// LDS: phase-1 arrays (1.7K floats) alias the 16K-float phase-2 reduce buffer.
__global__ __launch_bounds__(512) void k_steps(
        const float* __restrict__ emb, const unsigned short* __restrict__ WdaT,
        const float* __restrict__ bda, const float* __restrict__ Wfa,
        const float* __restrict__ bfa, const int* __restrict__ wsi,
        float* __restrict__ h, float* __restrict__ c,
        const unsigned short* __restrict__ att1b, const unsigned short* __restrict__ encb,
        const unsigned short* __restrict__ WfbT, const float* __restrict__ bfb,
        unsigned short* __restrict__ xcatb, float* __restrict__ out,
        const unsigned short* __restrict__ W2b, const float* __restrict__ bih,
        const float* __restrict__ bhh, unsigned short* __restrict__ histb) {
    cg::grid_group grid = cg::this_grid();
    __shared__ float smem[16384];             // 64 KB
    float* const s_h    = smem;               // 512
    float* const s_att2 = smem + 512;         // 512
    float* const s_e    = smem + 1024;        // 196
    float* const s_al   = smem + 1232;        // 196
    float* const sred   = smem + 1440;        // 256

    int bid  = blockIdx.x;
    int b    = bid & 31, dgrp = bid >> 5;
    int tid  = threadIdx.x, lane = tid & 63;
    int wd   = tid >> 6;
    int d    = dgrp * 512 + tid;
    int declen_b = wsi[NB + b];

    // loop-invariant hoists (phase 1)
    float bda_t = bda[tid];
    float bfa0  = bfa[0];
    float wfr[8];
    #pragma unroll
    for (int u = 0; u < 8; u++) wfr[u] = Wfa[lane * 8 + u];
    float bfb_d = bfb[d];
    const unsigned short* wdar = WdaT + (size_t)tid * NH;
    const unsigned short* er   = encb + (size_t)b * (NP * NDE) + d;
    const unsigned short* wfbr = WfbT + (size_t)d * NH;

    // loop-invariant hoists (phase 2, blocks 0..31)
    int j0 = bid * 16;
    int p2_b = tid >> 4, p2_j = tid & 15;
    float bsum[4] = {0.f, 0.f, 0.f, 0.f};
    int declen_p2 = 0;
    if (bid < 32) {
        #pragma unroll
        for (int q = 0; q < 4; q++) {
            int n = q * 512 + j0 + p2_j;
            bsum[q] = bih[n] + bhh[n];
        }
        declen_p2 = wsi[NB + p2_b];
    }

    for (int t = 0; t < NTD; ++t) {
        // ---------- phase 1 ----------
        s_h[tid] = h[(size_t)b * NH + tid];
        if (dgrp == 0) {
            int tok = wsi[2 * NB + b * NT + t];
            xcatb[(size_t)b * NKX + tid] = f2bf(emb[(size_t)tok * NE + tid]);
        }
        __syncthreads();

        // att2[n=tid] = bda[n] + h . WdaT[n]  (4 accumulator chains)
        {
            float a0 = bda_t, a1 = 0.f, a2 = 0.f, a3 = 0.f;
            for (int k0 = 0; k0 < NH; k0 += 32) {
                bf16x8 w0 = *(const bf16x8*)(wdar + k0);
                bf16x8 w1 = *(const bf16x8*)(wdar + k0 + 8);
                bf16x8 w2 = *(const bf16x8*)(wdar + k0 + 16);
                bf16x8 w3 = *(const bf16x8*)(wdar + k0 + 24);
                #pragma unroll
                for (int u = 0; u < 8; u++) {
                    a0 = fmaf(s_h[k0 + u],      bf2f((unsigned short)w0[u]), a0);
                    a1 = fmaf(s_h[k0 + 8 + u],  bf2f((unsigned short)w1[u]), a1);
                    a2 = fmaf(s_h[k0 + 16 + u], bf2f((unsigned short)w2[u]), a2);
                    a3 = fmaf(s_h[k0 + 24 + u], bf2f((unsigned short)w3[u]), a3);
                }
            }
            s_att2[tid] = (a0 + a1) + (a2 + a3);
        }
        __syncthreads();

        // e-scores over 8 waves
        {
            float a2r[8];
            #pragma unroll
            for (int u = 0; u < 8; u++) a2r[u] = s_att2[lane * 8 + u];
            for (int p = wd; p < NP; p += 8) {
                bf16x8 a8 = *(const bf16x8*)(att1b + ((size_t)b * NP + p) * NA + lane * 8);
                float part = 0.f;
                #pragma unroll
                for (int u = 0; u < 8; u++) {
                    float x = bf2f((unsigned short)a8[u]) + a2r[u];
                    part = fmaf(fmaxf(x, 0.f), wfr[u], part);
                }
                #pragma unroll
                for (int off = 32; off > 0; off >>= 1) part += __shfl_down(part, off);
                if (lane == 0) s_e[p] = part + bfa0;
            }
        }
        __syncthreads();

        // softmax over 196
        if (tid < 256) sred[tid] = (tid < NP) ? s_e[tid] : -1e30f;
        __syncthreads();
        for (int s = 128; s > 0; s >>= 1) {
            if (tid < s) sred[tid] = fmaxf(sred[tid], sred[tid + s]);
            __syncthreads();
        }
        float mx = sred[0];
        __syncthreads();
        float ev = (tid < NP) ? expf(s_e[tid] - mx) : 0.f;
        if (tid < 256) sred[tid] = ev;
        __syncthreads();
        for (int s = 128; s > 0; s >>= 1) {
            if (tid < s) sred[tid] += sred[tid + s];
            __syncthreads();
        }
        float inv = 1.f / sred[0];
        if (tid < NP) {
            float a = ev * inv;
            s_al[tid] = a;
            if (dgrp == 0) {
                out[OUT_ALPHA + ((size_t)b * NTD + t) * NP + tid] =
                    (declen_b > t) ? a : 0.f;
            }
        }
        __syncthreads();

        // d-slice awe (4 chains, deep load window) + gate -> xcat[512+d]
        {
            float aw0 = 0.f, aw1 = 0.f, aw2 = 0.f, aw3 = 0.f;
            #pragma unroll 6
            for (int p = 0; p < 192; p += 8) {
                aw0 = fmaf(s_al[p + 0], bf2f(er[(size_t)(p + 0) * NDE]), aw0);
                aw1 = fmaf(s_al[p + 1], bf2f(er[(size_t)(p + 1) * NDE]), aw1);
                aw2 = fmaf(s_al[p + 2], bf2f(er[(size_t)(p + 2) * NDE]), aw2);
                aw3 = fmaf(s_al[p + 3], bf2f(er[(size_t)(p + 3) * NDE]), aw3);
                aw0 = fmaf(s_al[p + 4], bf2f(er[(size_t)(p + 4) * NDE]), aw0);
                aw1 = fmaf(s_al[p + 5], bf2f(er[(size_t)(p + 5) * NDE]), aw1);
                aw2 = fmaf(s_al[p + 6], bf2f(er[(size_t)(p + 6) * NDE]), aw2);
                aw3 = fmaf(s_al[p + 7], bf2f(er[(size_t)(p + 7) * NDE]), aw3);
            }
            aw0 = fmaf(s_al[192], bf2f(er[(size_t)192 * NDE]), aw0);
            aw1 = fmaf(s_al[193], bf2f(er[(size_t)193 * NDE]), aw1);
            aw2 = fmaf(s_al[194], bf2f(er[(size_t)194 * NDE]), aw2);
            aw3 = fmaf(s_al[195], bf2f(er[(size_t)195 * NDE]), aw3);
            float aw = (aw0 + aw1) + (aw2 + aw3);

            float g0 = bfb_d, g1 = 0.f, g2 = 0.f, g3 = 0.f;
            for (int k0 = 0; k0 < NH; k0 += 32) {
                bf16x8 w0 = *(const bf16x8*)(wfbr + k0);
                bf16x8 w1 = *(const bf16x8*)(wfbr + k0 + 8);
                bf16x8 w2 = *(const bf16x8*)(wfbr + k0 + 16);
                bf16x8 w3 = *(const bf16x8*)(wfbr + k0 + 24);
                #pragma unroll
                for (int u = 0; u < 8; u++) {
                    g0 = fmaf(s_h[k0 + u],      bf2f((unsigned short)w0[u]), g0);
                    g1 = fmaf(s_h[k0 + 8 + u],  bf2f((unsigned short)w1[u]), g1);
                    g2 = fmaf(s_h[k0 + 16 + u], bf2f((unsigned short)w2[u]), g2);
                    g3 = fmaf(s_h[k0 + 24 + u], bf2f((unsigned short)w3[u]), g3);
                }
            }
            float g = (g0 + g1) + (g2 + g3);
            xcatb[(size_t)b * NKX + 512 + d] = f2bf(sigm(g) * aw);
        }

        grid.sync();

        // ---------- phase 2 (blocks 0..31) ----------
        if (bid < 32) {
            float* const red = smem;          // [8][8][4][64] floats
            int w = tid >> 6, ln = lane & 15, quad = lane >> 4;
            f32x4 acc[8] = {};
            int kb = w * 384;
            for (int ks = 0; ks < 12; ks++) {
                int k = kb + ks * 32 + quad * 8;
                bf16x8 a0v = *(const bf16x8*)(xcatb + (size_t)ln * NKX + k);
                bf16x8 a1v = *(const bf16x8*)(xcatb + (size_t)(16 + ln) * NKX + k);
                #pragma unroll
                for (int q = 0; q < 4; q++) {
                    bf16x8 bq = *(const bf16x8*)(W2b + (size_t)(q * 512 + j0 + ln) * NKX + k);
                    acc[q * 2]     = MFMA16(a0v, bq, acc[q * 2]);
                    acc[q * 2 + 1] = MFMA16(a1v, bq, acc[q * 2 + 1]);
                }
            }
            #pragma unroll
            for (int f = 0; f < 8; f++)
                #pragma unroll
                for (int r = 0; r < 4; r++)
                    red[((w * 8 + f) * 4 + r) * 64 + lane] = acc[f][r];
            __syncthreads();
            {
                int bb = p2_b, j = p2_j;
                int mh = bb >> 4, row = bb & 15, reg = row & 3;
                int lq = ((row >> 2) << 4) | j;
                float g4[4];
                #pragma unroll
                for (int q = 0; q < 4; q++) {
                    float s = bsum[q];
                    #pragma unroll
                    for (int w2 = 0; w2 < 8; w2++)
                        s += red[((w2 * 8 + q * 2 + mh) * 4 + reg) * 64 + lq];
                    g4[q] = s;
                }
                int jg = j0 + j;
                float hv;
                if (declen_p2 > t) {
                    float cn = sigm(g4[1]) * c[(size_t)bb * NH + jg] + sigm(g4[0]) * tanhf(g4[2]);
                    hv = sigm(g4[3]) * tanhf(cn);
                    c[(size_t)bb * NH + jg] = cn;
                    h[(size_t)bb * NH + jg] = hv;
                    xcatb[(size_t)bb * NKX + 2560 + jg] = f2bf(hv);
                } else {
                    hv = h[(size_t)bb * NH + jg];
                }
                histb[((size_t)t * NB + bb) * NH + jg] = f2bf(hv);
            }
        }

        grid.sync();
    }
}

// FINAL: preds = hist @ Wout + bout (masked). grid (118 n-tiles, 2 m-groups),
// each block loops 5 m-tiles so its WoutT tile is re-read from L2/L3, not HBM.
static constexpr int HP = 520;      // padded LDS row stride (bf16 elems)
__global__ __launch_bounds__(256) void k_preds_all(const unsigned short* __restrict__ WoutT,
        const float* __restrict__ bout, const unsigned short* __restrict__ histb,
        const int* __restrict__ wsi, float* __restrict__ out) {
    __shared__ unsigned short s_hist[64 * HP];   // ~66.5 KB
    int tid = threadIdx.x;
    int w = tid >> 6, lane = tid & 63, ln = lane & 15, quad = lane >> 4;
    int n0 = blockIdx.x * 256 + w * 64;
    for (int mt = 0; mt < 5; ++mt) {
        int m0 = (blockIdx.y * 5 + mt) * 64;
        __syncthreads();                          // LDS reuse guard
        for (int i = tid; i < 64 * 64; i += 256) {
            int r = i >> 6, cc = i & 63;
            *(bf16x8*)(&s_hist[r * HP + cc * 8]) =
                *(const bf16x8*)(histb + (size_t)(m0 + r) * NH + cc * 8);
        }
        __syncthreads();
        f32x4 acc[4][4] = {};
        for (int k0 = 0; k0 < NH; k0 += 32) {
            bf16x8 bfr[4], afr[4];
            #pragma unroll
            for (int j = 0; j < 4; j++) {
                int n = n0 + j * 16 + ln;
                int nc = (n < NV) ? n : (NV - 1);
                bfr[j] = *(const bf16x8*)(WoutT + (size_t)nc * NH + k0 + quad * 8);
            }
            #pragma unroll
            for (int i = 0; i < 4; i++)
                afr[i] = *(const bf16x8*)(&s_hist[(i * 16 + ln) * HP + k0 + quad * 8]);
            #pragma unroll
            for (int i = 0; i < 4; i++)
                #pragma unroll
                for (int j = 0; j < 4; j++)
                    acc[i][j] = MFMA16(afr[i], bfr[j], acc[i][j]);
        }
        #pragma unroll
        for (int j = 0; j < 4; j++) {
            int n = n0 + j * 16 + ln;
            if (n >= NV) continue;
            float bo = bout[n];
            #pragma unroll
            for (int i = 0; i < 4; i++) {
                #pragma unroll
                for (int r = 0; r < 4; r++) {
                    int m = m0 + i * 16 + quad * 4 + r;
                    int tt = m >> 5, b = m & 31;
                    int active = wsi[NB + b] > tt;
                    out[OUT_PRED + ((size_t)b * NTD + tt) * NV + n] =
                        active ? (acc[i][j][r] + bo) : 0.f;
                }
            }
        }
    }
}

// ---------------- launch ----------------
extern "C" void kernel_launch(void* const* d_in, const int* in_sizes, int n_in,
                              void* d_out, int out_size, void* d_ws, size_t ws_size,
                              hipStream_t stream) {
    (void)in_sizes; (void)n_in; (void)out_size; (void)ws_size;
    const float* feat     = (const float*)d_in[0];
    const int*   captions = (const int*)d_in[1];
    const int*   clen     = (const int*)d_in[2];
    const float* emb      = (const float*)d_in[3];
    const float* Wea      = (const float*)d_in[4];
    const float* bea      = (const float*)d_in[5];
    const float* Wda      = (const float*)d_in[6];
    const float* bda      = (const float*)d_in[7];
    const float* Wfa      = (const float*)d_in[8];
    const float* bfa      = (const float*)d_in[9];
    const float* Wih      = (const float*)d_in[10];
    const float* bih      = (const float*)d_in[11];
    const float* Whh      = (const float*)d_in[12];
    const float* bhh      = (const float*)d_in[13];
    const float* Wh0      = (const float*)d_in[14];
    const float* bh0      = (const float*)d_in[15];
    const float* Wc0      = (const float*)d_in[16];
    const float* bc0      = (const float*)d_in[17];
    const float* Wfb      = (const float*)d_in[18];
    const float* bfb      = (const float*)d_in[19];
    const float* Wout     = (const float*)d_in[20];
    const float* bout     = (const float*)d_in[21];
    float* out = (float*)d_out;
    int*   wsi = (int*)d_ws;
    float* wsf = (float*)d_ws;

    float* W_h     = wsf + WS_H;
    float* W_c     = wsf + WS_C;
    float* W_mean  = wsf + WS_MEAN;
    unsigned short* W_xcatb = (unsigned short*)(wsf + WS_XCATB);
    unsigned short* W_att1b = (unsigned short*)(wsf + WS_ATT1B);
    unsigned short* W_encb  = (unsigned short*)(wsf + WS_ENCB);
    unsigned short* W_w2b   = (unsigned short*)(wsf + WS_W2B);
    unsigned short* W_wdaT  = (unsigned short*)(wsf + WS_WDAT);
    unsigned short* W_weaT  = (unsigned short*)(wsf + WS_WEAT);
    unsigned short* W_woutT = (unsigned short*)(wsf + WS_WOUTT);
    unsigned short* W_wfbT  = (unsigned short*)(wsf + WS_WFBT);
    unsigned short* W_meanb = (unsigned short*)(wsf + WS_MEANB);
    unsigned short* W_wh0T  = (unsigned short*)(wsf + WS_WH0T);
    unsigned short* W_wc0T  = (unsigned short*)(wsf + WS_WC0T);
    unsigned short* W_hist  = (unsigned short*)(wsf + WS_HIST);

    k_sort<<<1, 64, 0, stream>>>(captions, clen, out, wsi);
    k_prep<<<256, 256, 0, stream>>>(feat, wsi, W_encb, W_mean, W_meanb);
    k_trbf<<<dim3(16, 64), 256, 0, stream>>>(Wh0, W_wh0T, 2048, 512);
    k_trbf<<<dim3(16, 64), 256, 0, stream>>>(Wc0, W_wc0T, 2048, 512);
    k_h0c0m<<<16, 256, 0, stream>>>(W_meanb, W_wh0T, W_wc0T, bh0, bc0,
                                    W_h, W_c, W_xcatb);
    k_w2b<<<dim3(12, 2048), 256, 0, stream>>>(Wih, Whh, W_w2b);
    k_trbf<<<dim3(16, 16), 256, 0, stream>>>(Wda, W_wdaT, 512, 512);
    k_trbf<<<dim3(16, 64), 256, 0, stream>>>(Wea, W_weaT, 2048, 512);
    k_trbf<<<dim3(938, 16), 256, 0, stream>>>(Wout, W_woutT, 512, 30000);
    k_trbf<<<dim3(64, 16), 256, 0, stream>>>(Wfb, W_wfbT, 512, 2048);
    k_att1<<<dim3(98, 2), 256, 0, stream>>>(W_encb, W_weaT, bea, W_att1b);

    // all 20 decoder steps in one persistent cooperative kernel
    {
        void* kargs[] = { (void*)&emb,     (void*)&W_wdaT, (void*)&bda,
                          (void*)&Wfa,     (void*)&bfa,    (void*)&wsi,
                          (void*)&W_h,     (void*)&W_c,    (void*)&W_att1b,
                          (void*)&W_encb,  (void*)&W_wfbT, (void*)&bfb,
                          (void*)&W_xcatb, (void*)&out,    (void*)&W_w2b,
                          (void*)&bih,     (void*)&bhh,    (void*)&W_hist };
        hipLaunchCooperativeKernel((const void*)k_steps, dim3(128), dim3(512),
                                   kargs, 0, stream);
    }

    k_preds_all<<<dim3(118, 2), 256, 0, stream>>>(W_woutT, bout, W_hist, wsi, out);
}

// Round 2
// 1377.605 us; speedup vs baseline: 2.1003x; 2.1003x over previous
//
#include <hip/hip_runtime.h>
#include <cstdint>
#include <cstddef>

// ---------------- problem constants ----------------
static constexpr int NB  = 32;      // batch
static constexpr int NT  = 22;      // caption length T
static constexpr int NP  = 196;     // pixels 14*14
static constexpr int NDE = 2048;    // encoder dim
static constexpr int NE  = 512;     // embed dim
static constexpr int NH  = 512;     // hidden
static constexpr int NA  = 512;     // attention dim
static constexpr int NV  = 30000;   // vocab
static constexpr int NTD = 20;      // Tdec = T-2
static constexpr int NKX = 3072;    // E + DE + H (concat x | h)

// ---------------- output offsets (floats) ----------------
static constexpr size_t OUT_PRED  = 0;
static constexpr size_t OUT_ALPHA = (size_t)NB*NTD*NV;            // 19,200,000
static constexpr size_t OUT_CAPS  = OUT_ALPHA + (size_t)NB*NTD*NP;// 19,325,440
static constexpr size_t OUT_LEN   = OUT_CAPS + (size_t)NB*NT;     // 19,326,144
static constexpr size_t OUT_SIDX  = OUT_LEN + NB;                 // 19,326,176

// ---------------- ws layout (float offsets) ----------------
// int region: [0,32) sidx | [32,64) declen | [64,768) caps_i
static constexpr size_t WS_H     = 768;
static constexpr size_t WS_C     = 17152;
static constexpr size_t WS_ATT2F = 33536;     // fp32 [32][512]  (reuses old mean slot)
static constexpr size_t WS_GATEF = 49920;     // fp32 [32][2048] -> ends 115,456
static constexpr size_t WS_XCATB = 121728;    // bf16 [32][3072]
static constexpr size_t WS_ATT1B = 170880;    // bf16 [6272][512]
static constexpr size_t WS_ENCB  = 1776512;   // bf16 [32][196][2048]
static constexpr size_t WS_W2B   = 8199040;   // bf16 [2048][3072]
static constexpr size_t WS_WDAT  = 11344768;  // bf16 [512][512]   (WdaT[n][k])
static constexpr size_t WS_WEAT  = 11475840;  // bf16 [512][2048]  (WeaT[n][k])
static constexpr size_t WS_WOUTT = 12000128;  // bf16 [30000][512] (WoutT[n][k])
static constexpr size_t WS_WFBT  = 19680128;  // bf16 [2048][512]  (WfbT[d][k])
static constexpr size_t WS_MEANB = 20204416;  // bf16 [32][2048]
static constexpr size_t WS_WH0T  = 20237184;  // bf16 [512][2048]
static constexpr size_t WS_WC0T  = 20761472;  // bf16 [512][2048]
static constexpr size_t WS_HIST  = 21285760;  // bf16 [640][512] (h history, m=t*32+b)
// end = 21,449,600 floats ~= 81.8 MB

// ---------------- MFMA types & helpers ----------------
typedef __attribute__((ext_vector_type(8))) short bf16x8;
typedef __attribute__((ext_vector_type(4))) float f32x4;
#define MFMA16(a,b,c) __builtin_amdgcn_mfma_f32_16x16x32_bf16(a,b,c,0,0,0)

__device__ __forceinline__ float bf2f(unsigned short u) {
    return __uint_as_float(((unsigned)u) << 16);
}
__device__ __forceinline__ unsigned short f2bf(float f) {
    unsigned u = __float_as_uint(f);
    u += 0x7FFF + ((u >> 16) & 1);      // RTNE
    return (unsigned short)(u >> 16);
}
__device__ __forceinline__ float sigm(float x) { return 1.f / (1.f + expf(-x)); }

// ---------------- prelude kernels ----------------

__global__ void k_sort(const int* __restrict__ cap, const int* __restrict__ clen,
                       float* __restrict__ out, int* __restrict__ wsi) {
    __shared__ int slen[NB], ssid[NB];
    int i = threadIdx.x;
    if (i < NB) slen[i] = clen[i];
    __syncthreads();
    if (i < NB) {
        int li = slen[i], r = 0;
        for (int j = 0; j < NB; j++) {
            int lj = slen[j];
            if (lj > li || (lj == li && j < i)) r++;
        }
        ssid[r] = i;
    }
    __syncthreads();
    if (i < NB) {
        int src = ssid[i];
        wsi[i] = src;
        int L = slen[src];
        wsi[NB + i] = L - 1;
        out[OUT_LEN + i]  = (float)L;
        out[OUT_SIDX + i] = (float)src;
        for (int tt = 0; tt < NT; tt++) {
            int tok = cap[tt * NB + src];
            wsi[2 * NB + i * NT + tt] = tok;
            out[OUT_CAPS + i * NT + tt] = (float)tok;
        }
    }
}

// sorted-gather feat -> enc bf16, plus per-(b,d) mean (bf16)
__global__ void k_prep(const float* __restrict__ feat, const int* __restrict__ wsi,
                       unsigned short* __restrict__ encb,
                       unsigned short* __restrict__ meanb) {
    int g = blockIdx.x * 256 + threadIdx.x;   // 65536 = 32*2048
    int b = g >> 11, d = g & 2047;
    const float* src = feat + (size_t)wsi[b] * (NP * NDE) + d;
    unsigned short* dst = encb + (size_t)b * (NP * NDE) + d;
    float s = 0.f;
    for (int p = 0; p < NP; p++) {
        float v = src[(size_t)p * NDE];
        s += v;
        dst[(size_t)p * NDE] = f2bf(v);
    }
    float m = s * (1.0f / 196.0f);
    meanb[(size_t)b * NDE + d] = f2bf(m);
}

// h0/c0 via MFMA: M=32, N=512 each; 16 blocks (8 h-tiles, 8 c-tiles)
__global__ __launch_bounds__(256) void k_h0c0m(const unsigned short* __restrict__ meanb,
        const unsigned short* __restrict__ WH0T, const unsigned short* __restrict__ WC0T,
        const float* __restrict__ bh0, const float* __restrict__ bc0,
        float* __restrict__ h, float* __restrict__ c, unsigned short* __restrict__ xcatb) {
    int tid = threadIdx.x;
    int w = tid >> 6, lane = tid & 63, ln = lane & 15, quad = lane >> 4;
    int which = blockIdx.x >> 3;
    int n = (blockIdx.x & 7) * 64 + w * 16 + ln;
    const unsigned short* WT = which ? WC0T : WH0T;
    f32x4 acc0 = {0.f, 0.f, 0.f, 0.f}, acc1 = {0.f, 0.f, 0.f, 0.f};
    for (int k0 = 0; k0 < NDE; k0 += 32) {
        bf16x8 bfr = *(const bf16x8*)(WT + (size_t)n * NDE + k0 + quad * 8);
        bf16x8 a0 = *(const bf16x8*)(meanb + (size_t)ln * NDE + k0 + quad * 8);
        bf16x8 a1 = *(const bf16x8*)(meanb + (size_t)(16 + ln) * NDE + k0 + quad * 8);
        acc0 = MFMA16(a0, bfr, acc0);
        acc1 = MFMA16(a1, bfr, acc1);
    }
    float bias = which ? bc0[n] : bh0[n];
    #pragma unroll
    for (int r = 0; r < 4; r++) {
        int b0r = quad * 4 + r;
        float v0 = acc0[r] + bias, v1 = acc1[r] + bias;
        if (which) {
            c[(size_t)b0r * NH + n] = v0;
            c[(size_t)(16 + b0r) * NH + n] = v1;
        } else {
            h[(size_t)b0r * NH + n] = v0;
            h[(size_t)(16 + b0r) * NH + n] = v1;
            xcatb[(size_t)b0r * NKX + 2560 + n] = f2bf(v0);
            xcatb[(size_t)(16 + b0r) * NKX + 2560 + n] = f2bf(v1);
        }
    }
}

// W2b[n][k] = bf16( k<2560 ? Wih[n][k] : Whh[n][k-2560] )
__global__ void k_w2b(const float* __restrict__ Wih, const float* __restrict__ Whh,
                      unsigned short* __restrict__ W2b) {
    int k = blockIdx.x * 256 + threadIdx.x;   // 0..3071
    int n = blockIdx.y;                       // 0..2047
    float v = (k < 2560) ? Wih[(size_t)n * 2560 + k]
                         : Whh[(size_t)n * 512 + (k - 2560)];
    W2b[(size_t)n * NKX + k] = f2bf(v);
}

// fp32 [R][C] -> bf16 [C][R] (R multiple of 32; C bounds-checked)
__global__ void k_trbf(const float* __restrict__ src, unsigned short* __restrict__ dst,
                       int R, int C) {
    __shared__ float s[32][33];
    int c0 = blockIdx.x * 32, r0 = blockIdx.y * 32;
    int tx = threadIdx.x & 31, ty = threadIdx.x >> 5;  // ty 0..7
    #pragma unroll
    for (int i = 0; i < 4; i++) {
        int rr = ty * 4 + i;
        int cc = c0 + tx;
        s[rr][tx] = (cc < C) ? src[(size_t)(r0 + rr) * C + cc] : 0.f;
    }
    __syncthreads();
    #pragma unroll
    for (int i = 0; i < 4; i++) {
        int cc = ty * 4 + i;
        int cg = c0 + cc;
        if (cg < C) dst[(size_t)cg * R + r0 + tx] = f2bf(s[tx][cc]);
    }
}

// att1 = enc @ Wea + bea  (MFMA bf16): M=6272, N=512, K=2048 -> att1b bf16
__global__ __launch_bounds__(256) void k_att1(const unsigned short* __restrict__ encb,
        const unsigned short* __restrict__ WeaT, const float* __restrict__ bea,
        unsigned short* __restrict__ att1b) {
    __shared__ unsigned short As[64 * 40];    // 64 m x 32 k, stride 40
    int m0 = blockIdx.x * 64;
    int nb = blockIdx.y * 256;
    int tid = threadIdx.x;
    int w = tid >> 6, lane = tid & 63, ln = lane & 15, quad = lane >> 4;
    int nbase = nb + w * 64;
    f32x4 acc[4][4] = {};
    int sm = tid >> 2, sc = tid & 3;
    for (int k0 = 0; k0 < NDE; k0 += 32) {
        bf16x8 v = *(const bf16x8*)(encb + (size_t)(m0 + sm) * NDE + k0 + sc * 8);
        __syncthreads();
        *(bf16x8*)(&As[sm * 40 + sc * 8]) = v;
        __syncthreads();
        bf16x8 a[4], bb[4];
        #pragma unroll
        for (int i = 0; i < 4; i++)
            a[i] = *(const bf16x8*)(&As[(i * 16 + ln) * 40 + quad * 8]);
        #pragma unroll
        for (int j = 0; j < 4; j++)
            bb[j] = *(const bf16x8*)(WeaT + (size_t)(nbase + j * 16 + ln) * NDE + k0 + quad * 8);
        #pragma unroll
        for (int i = 0; i < 4; i++)
            #pragma unroll
            for (int j = 0; j < 4; j++)
                acc[i][j] = MFMA16(a[i], bb[j], acc[i][j]);
    }
    #pragma unroll
    for (int i = 0; i < 4; i++)
        #pragma unroll
        for (int j = 0; j < 4; j++) {
            int n = nbase + j * 16 + ln;
            float be = bea[n];
            #pragma unroll
            for (int r = 0; r < 4; r++) {
                int m = m0 + i * 16 + quad * 4 + r;
                att1b[(size_t)m * NA + n] = f2bf(acc[i][j][r] + be);
            }
        }
}

// ---------------- per-step kernels ----------------

// kA: att2_all = H @ WdaT + bda  (N 0..511) and gate_lin = H @ WfbT + bfb
// (N 512..2559) as one M=32, N=2560, K=512 MFMA GEMM. H = xcatb[:,2560:3072].
// grid 40 blocks x 256 threads.
__global__ __launch_bounds__(256) void k_hproj(const unsigned short* __restrict__ xcatb,
        const unsigned short* __restrict__ WdaT, const unsigned short* __restrict__ WfbT,
        const float* __restrict__ bda, const float* __restrict__ bfb,
        float* __restrict__ att2f, float* __restrict__ gatef) {
    int tid = threadIdx.x;
    int w = tid >> 6, lane = tid & 63, ln = lane & 15, quad = lane >> 4;
    int n = blockIdx.x * 64 + w * 16 + ln;    // 0..2559
    const unsigned short* wrow = (n < 512) ? (WdaT + (size_t)n * NH)
                                           : (WfbT + (size_t)(n - 512) * NH);
    f32x4 acc0 = {0.f, 0.f, 0.f, 0.f}, acc1 = {0.f, 0.f, 0.f, 0.f};
    for (int k0 = 0; k0 < NH; k0 += 32) {
        bf16x8 bfr = *(const bf16x8*)(wrow + k0 + quad * 8);
        bf16x8 a0 = *(const bf16x8*)(xcatb + (size_t)ln * NKX + 2560 + k0 + quad * 8);
        bf16x8 a1 = *(const bf16x8*)(xcatb + (size_t)(16 + ln) * NKX + 2560 + k0 + quad * 8);
        acc0 = MFMA16(a0, bfr, acc0);
        acc1 = MFMA16(a1, bfr, acc1);
    }
    float bias = (n < 512) ? bda[n] : bfb[n - 512];
    #pragma unroll
    for (int r = 0; r < 4; r++) {
        int m0 = quad * 4 + r;
        float v0 = acc0[r] + bias, v1 = acc1[r] + bias;
        if (n < 512) {
            att2f[(size_t)m0 * NA + n] = v0;
            att2f[(size_t)(16 + m0) * NA + n] = v1;
        } else {
            gatef[(size_t)m0 * NDE + (n - 512)] = v0;
            gatef[(size_t)(16 + m0) * NDE + (n - 512)] = v1;
        }
    }
}

// kB: scores + softmax + alpha-out + emb gather + awe (wave-per-p) + gate-mul
// grid (32 b, 4 dgrp) x 512 threads; dgrp handles a 512-wide d-slice.
__global__ __launch_bounds__(512) void k_attn(const float* __restrict__ emb,
        const float* __restrict__ att2f, const float* __restrict__ gatef,
        const float* __restrict__ Wfa, const float* __restrict__ bfa,
        const int* __restrict__ wsi, const unsigned short* __restrict__ att1b,
        const unsigned short* __restrict__ encb, unsigned short* __restrict__ xcatb,
        float* __restrict__ out, int t) {
    int b = blockIdx.x, dgrp = blockIdx.y;
    int tid = threadIdx.x, lane = tid & 63, wv = tid >> 6;
    __shared__ float s_att2[NA];
    __shared__ float s_e[NP];
    __shared__ float s_al[NP];
    __shared__ float sred[256];
    __shared__ float s_part[8 * 512];         // 16 KB wave-partial awe

    // A: att2 -> LDS; emb gather (dgrp 0 only)
    s_att2[tid] = att2f[(size_t)b * NA + tid];
    if (dgrp == 0) {
        int tok = wsi[2 * NB + b * NT + t];
        xcatb[(size_t)b * NKX + tid] = f2bf(emb[(size_t)tok * NE + tid]);
    }
    __syncthreads();

    // B: e-scores, wave wv handles p = wv, wv+8, ...
    {
        float a2r[8], wfr[8];
        #pragma unroll
        for (int u = 0; u < 8; u++) {
            a2r[u] = s_att2[lane * 8 + u];
            wfr[u] = Wfa[lane * 8 + u];
        }
        for (int p = wv; p < NP; p += 8) {
            bf16x8 a8 = *(const bf16x8*)(att1b + ((size_t)b * NP + p) * NA + lane * 8);
            float part = 0.f;
            #pragma unroll
            for (int u = 0; u < 8; u++) {
                float x = bf2f((unsigned short)a8[u]) + a2r[u];
                part = fmaf(fmaxf(x, 0.f), wfr[u], part);
            }
            #pragma unroll
            for (int off = 32; off > 0; off >>= 1) part += __shfl_down(part, off);
            if (lane == 0) s_e[p] = part + bfa[0];
        }
    }
    __syncthreads();

    // C: softmax over 196
    if (tid < 256) sred[tid] = (tid < NP) ? s_e[tid] : -1e30f;
    __syncthreads();
    for (int s = 128; s > 0; s >>= 1) {
        if (tid < s) sred[tid] = fmaxf(sred[tid], sred[tid + s]);
        __syncthreads();
    }
    float mx = sred[0];
    __syncthreads();
    float ev = (tid < NP) ? expf(s_e[tid] - mx) : 0.f;
    if (tid < 256) sred[tid] = ev;
    __syncthreads();
    for (int s = 128; s > 0; s >>= 1) {
        if (tid < s) sred[tid] += sred[tid + s];
        __syncthreads();
    }
    float inv = 1.f / sred[0];
    if (tid < NP) {
        float a = ev * inv;
        s_al[tid] = a;
        if (dgrp == 0) {
            int active = wsi[NB + b] > t;
            out[OUT_ALPHA + ((size_t)b * NTD + t) * NP + tid] = active ? a : 0.f;
        }
    }
    __syncthreads();

    // D: awe — wave-per-p partials, coalesced 1KB loads, independent iters
    {
        float aw[8] = {0.f, 0.f, 0.f, 0.f, 0.f, 0.f, 0.f, 0.f};
        const unsigned short* base = encb + (size_t)b * (NP * NDE) + dgrp * 512 + lane * 8;
        for (int p = wv; p < NP; p += 8) {
            bf16x8 ev8 = *(const bf16x8*)(base + (size_t)p * NDE);
            float al = s_al[p];
            #pragma unroll
            for (int u = 0; u < 8; u++)
                aw[u] = fmaf(al, bf2f((unsigned short)ev8[u]), aw[u]);
        }
        #pragma unroll
        for (int u = 0; u < 8; u++)
            s_part[wv * 512 + lane * 8 + u] = aw[u];
    }
    __syncthreads();

    // E: cross-wave reduce + gate multiply -> xcat[512+d]
    {
        int d = dgrp * 512 + tid;
        float s = 0.f;
        #pragma unroll
        for (int w = 0; w < 8; w++) s += s_part[w * 512 + tid];
        float g = sigm(gatef[(size_t)b * NDE + d]);
        xcatb[(size_t)b * NKX + 512 + d] = f2bf(g * s);
    }
}

// kC: gates GEMM (M=32, N=16/block over 128 blocks, K=3072 split over 8 waves)
// + LDS reduce + LSTM pointwise + hist. Block covers j0..j0+3 x 4 gate quadrants.
__global__ __launch_bounds__(512) void k_gates(const unsigned short* __restrict__ W2b,
        unsigned short* __restrict__ xcatb, const float* __restrict__ bih,
        const float* __restrict__ bhh, const int* __restrict__ wsi,
        float* __restrict__ h, float* __restrict__ c,
        unsigned short* __restrict__ histb, int t) {
    __shared__ float red[8][2][4][64];        // 16 KB
    int tid = threadIdx.x;
    int w = tid >> 6, lane = tid & 63, ln = lane & 15, quad = lane >> 4;
    int j0 = blockIdx.x * 4;
    int nrow = ((ln >> 2) << 9) + j0 + (ln & 3);   // (ln>>2)*512 + j0 + (ln&3)
    f32x4 acc0 = {0.f, 0.f, 0.f, 0.f}, acc1 = {0.f, 0.f, 0.f, 0.f};
    int kb = w * 384;
    for (int ks = 0; ks < 12; ks++) {
        int k = kb + ks * 32 + quad * 8;
        bf16x8 a0 = *(const bf16x8*)(xcatb + (size_t)ln * NKX + k);
        bf16x8 a1 = *(const bf16x8*)(xcatb + (size_t)(16 + ln) * NKX + k);
        bf16x8 bq = *(const bf16x8*)(W2b + (size_t)nrow * NKX + k);
        acc0 = MFMA16(a0, bq, acc0);
        acc1 = MFMA16(a1, bq, acc1);
    }
    #pragma unroll
    for (int r = 0; r < 4; r++) {
        red[w][0][r][lane] = acc0[r];
        red[w][1][r][lane] = acc1[r];
    }
    __syncthreads();
    if (tid < 128) {
        int b = tid >> 2, j = tid & 3;
        int mh = b >> 4, row = b & 15, reg = row & 3;
        int qb = (row >> 2) << 4;
        float g4[4];
        #pragma unroll
        for (int q = 0; q < 4; q++) {
            int idx = (q << 2) | j;
            int n = q * 512 + j0 + j;
            float s = bih[n] + bhh[n];
            #pragma unroll
            for (int w2 = 0; w2 < 8; w2++) s += red[w2][mh][reg][qb | idx];
            g4[q] = s;
        }
        int jg = j0 + j;
        int active = wsi[NB + b] > t;
        float hv;
        if (active) {
            float cn = sigm(g4[1]) * c[(size_t)b * NH + jg] + sigm(g4[0]) * tanhf(g4[2]);
            hv = sigm(g4[3]) * tanhf(cn);
            c[(size_t)b * NH + jg] = cn;
            h[(size_t)b * NH + jg] = hv;
            xcatb[(size_t)b * NKX + 2560 + jg] = f2bf(hv);
        } else {
            hv = h[(size_t)b * NH + jg];
        }
        histb[((size_t)t * NB + b) * NH + jg] = f2bf(hv);
    }
}

// FINAL: preds = hist @ Wout + bout (masked). grid (118 n-tiles, 2 m-groups),
// each block loops 5 m-tiles so its WoutT tile is re-read from L2/L3, not HBM.
static constexpr int HP = 520;      // padded LDS row stride (bf16 elems)
__global__ __launch_bounds__(256) void k_preds_all(const unsigned short* __restrict__ WoutT,
        const float* __restrict__ bout, const unsigned short* __restrict__ histb,
        const int* __restrict__ wsi, float* __restrict__ out) {
    __shared__ unsigned short s_hist[64 * HP];   // ~66.5 KB
    int tid = threadIdx.x;
    int w = tid >> 6, lane = tid & 63, ln = lane & 15, quad = lane >> 4;
    int n0 = blockIdx.x * 256 + w * 64;
    for (int mt = 0; mt < 5; ++mt) {
        int m0 = (blockIdx.y * 5 + mt) * 64;
        __syncthreads();                          // LDS reuse guard
        for (int i = tid; i < 64 * 64; i += 256) {
            int r = i >> 6, cc = i & 63;
            *(bf16x8*)(&s_hist[r * HP + cc * 8]) =
                *(const bf16x8*)(histb + (size_t)(m0 + r) * NH + cc * 8);
        }
        __syncthreads();
        f32x4 acc[4][4] = {};
        for (int k0 = 0; k0 < NH; k0 += 32) {
            bf16x8 bfr[4], afr[4];
            #pragma unroll
            for (int j = 0; j < 4; j++) {
                int n = n0 + j * 16 + ln;
                int nc = (n < NV) ? n : (NV - 1);
                bfr[j] = *(const bf16x8*)(WoutT + (size_t)nc * NH + k0 + quad * 8);
            }
            #pragma unroll
            for (int i = 0; i < 4; i++)
                afr[i] = *(const bf16x8*)(&s_hist[(i * 16 + ln) * HP + k0 + quad * 8]);
            #pragma unroll
            for (int i = 0; i < 4; i++)
                #pragma unroll
                for (int j = 0; j < 4; j++)
                    acc[i][j] = MFMA16(afr[i], bfr[j], acc[i][j]);
        }
        #pragma unroll
        for (int j = 0; j < 4; j++) {
            int n = n0 + j * 16 + ln;
            if (n >= NV) continue;
            float bo = bout[n];
            #pragma unroll
            for (int i = 0; i < 4; i++) {
                #pragma unroll
                for (int r = 0; r < 4; r++) {
                    int m = m0 + i * 16 + quad * 4 + r;
                    int tt = m >> 5, b = m & 31;
                    int active = wsi[NB + b] > tt;
                    out[OUT_PRED + ((size_t)b * NTD + tt) * NV + n] =
                        active ? (acc[i][j][r] + bo) : 0.f;
                }
            }
        }
    }
}

// ---------------- launch ----------------
extern "C" void kernel_launch(void* const* d_in, const int* in_sizes, int n_in,
                              void* d_out, int out_size, void* d_ws, size_t ws_size,
                              hipStream_t stream) {
    (void)in_sizes; (void)n_in; (void)out_size; (void)ws_size;
    const float* feat     = (const float*)d_in[0];
    const int*   captions = (const int*)d_in[1];
    const int*   clen     = (const int*)d_in[2];
    const float* emb      = (const float*)d_in[3];
    const float* Wea      = (const float*)d_in[4];
    const float* bea      = (const float*)d_in[5];
    const float* Wda      = (const float*)d_in[6];
    const float* bda      = (const float*)d_in[7];
    const float* Wfa      = (const float*)d_in[8];
    const float* bfa      = (const float*)d_in[9];
    const float* Wih      = (const float*)d_in[10];
    const float* bih      = (const float*)d_in[11];
    const float* Whh      = (const float*)d_in[12];
    const float* bhh      = (const float*)d_in[13];
    const float* Wh0      = (const float*)d_in[14];
    const float* bh0      = (const float*)d_in[15];
    const float* Wc0      = (const float*)d_in[16];
    const float* bc0      = (const float*)d_in[17];
    const float* Wfb      = (const float*)d_in[18];
    const float* bfb      = (const float*)d_in[19];
    const float* Wout     = (const float*)d_in[20];
    const float* bout     = (const float*)d_in[21];
    float* out = (float*)d_out;
    int*   wsi = (int*)d_ws;
    float* wsf = (float*)d_ws;

    float* W_h     = wsf + WS_H;
    float* W_c     = wsf + WS_C;
    float* W_att2f = wsf + WS_ATT2F;
    float* W_gatef = wsf + WS_GATEF;
    unsigned short* W_xcatb = (unsigned short*)(wsf + WS_XCATB);
    unsigned short* W_att1b = (unsigned short*)(wsf + WS_ATT1B);
    unsigned short* W_encb  = (unsigned short*)(wsf + WS_ENCB);
    unsigned short* W_w2b   = (unsigned short*)(wsf + WS_W2B);
    unsigned short* W_wdaT  = (unsigned short*)(wsf + WS_WDAT);
    unsigned short* W_weaT  = (unsigned short*)(wsf + WS_WEAT);
    unsigned short* W_woutT = (unsigned short*)(wsf + WS_WOUTT);
    unsigned short* W_wfbT  = (unsigned short*)(wsf + WS_WFBT);
    unsigned short* W_meanb = (unsigned short*)(wsf + WS_MEANB);
    unsigned short* W_wh0T  = (unsigned short*)(wsf + WS_WH0T);
    unsigned short* W_wc0T  = (unsigned short*)(wsf + WS_WC0T);
    unsigned short* W_hist  = (unsigned short*)(wsf + WS_HIST);

    k_sort<<<1, 64, 0, stream>>>(captions, clen, out, wsi);
    k_prep<<<256, 256, 0, stream>>>(feat, wsi, W_encb, W_meanb);
    k_trbf<<<dim3(16, 64), 256, 0, stream>>>(Wh0, W_wh0T, 2048, 512);
    k_trbf<<<dim3(16, 64), 256, 0, stream>>>(Wc0, W_wc0T, 2048, 512);
    k_h0c0m<<<16, 256, 0, stream>>>(W_meanb, W_wh0T, W_wc0T, bh0, bc0,
                                    W_h, W_c, W_xcatb);
    k_w2b<<<dim3(12, 2048), 256, 0, stream>>>(Wih, Whh, W_w2b);
    k_trbf<<<dim3(16, 16), 256, 0, stream>>>(Wda, W_wdaT, 512, 512);
    k_trbf<<<dim3(16, 64), 256, 0, stream>>>(Wea, W_weaT, 2048, 512);
    k_trbf<<<dim3(938, 16), 256, 0, stream>>>(Wout, W_woutT, 512, 30000);
    k_trbf<<<dim3(64, 16), 256, 0, stream>>>(Wfb, W_wfbT, 512, 2048);
    k_att1<<<dim3(98, 2), 256, 0, stream>>>(W_encb, W_weaT, bea, W_att1b);

    for (int t = 0; t < NTD; t++) {
        k_hproj<<<40, 256, 0, stream>>>(W_xcatb, W_wdaT, W_wfbT, bda, bfb,
                                        W_att2f, W_gatef);
        k_attn<<<dim3(32, 4), 512, 0, stream>>>(emb, W_att2f, W_gatef, Wfa, bfa,
                                                wsi, W_att1b, W_encb, W_xcatb,
                                                out, t);
        k_gates<<<128, 512, 0, stream>>>(W_w2b, W_xcatb, bih, bhh, wsi,
                                         W_h, W_c, W_hist, t);
    }
    k_preds_all<<<dim3(118, 2), 256, 0, stream>>>(W_woutT, bout, W_hist, wsi, out);
}